// Round 15
// baseline (338.065 us; speedup 1.0000x reference)
//
#include <hip/hip_runtime.h>

#define N_PTS 1048576
#define NC 50000
#define SCAN_B 196   // scan blocks: 196*256 = 50176 >= NC

typedef int   i32x4  __attribute__((ext_vector_type(4)));
typedef float f32x4v __attribute__((ext_vector_type(4)));

__device__ __forceinline__ unsigned short bf16rne(float f) {
    unsigned u = __float_as_uint(f);
    u = (u + 0x7fffu + ((u >> 16) & 1u)) >> 16;
    return (unsigned short)u;
}
__device__ __forceinline__ f32x4v mfma16(i32x4 a, i32x4 b, f32x4v c) {
    asm("v_mfma_f32_16x16x32_bf16 %0, %1, %2, %0" : "+v"(c) : "v"(a), "v"(b));
    return c;
}
__device__ __forceinline__ int cvtpk(float lo, float hi) {
    int r;
    asm("v_cvt_pk_bf16_f32 %0, %1, %2" : "=v"(r) : "v"(lo), "v"(hi));
    return r;
}

// DPP within 16-lane rows; bound_ctrl=1 -> shifted-in 0.
#define DPPSHR(D, X) __builtin_amdgcn_update_dpp(0, (X), 0x110 | (D), 0xf, 0xf, true)
#define DPPSHL1(X)   __builtin_amdgcn_update_dpp(0, (X), 0x101, 0xf, 0xf, true)

// ---------------- weight prep: W2/W3/W4 fp32 -> bf16 ----------------
__global__ __launch_bounds__(256) void k_prep(
    const float* __restrict__ W2, const float* __restrict__ W3,
    const float* __restrict__ W4,
    unsigned short* __restrict__ W2bf, unsigned short* __restrict__ W3bf,
    unsigned short* __restrict__ W4bf)
{
    int i = blockIdx.x * 256 + threadIdx.x;   // 20480 total
    if (i < 8192)       W2bf[i]         = bf16rne(W2[i]);
    else if (i < 16384) W3bf[i - 8192]  = bf16rne(W3[i - 8192]);
    else                W4bf[i - 16384] = bf16rne(W4[i - 16384]);
}

// ---------------- counting sort: histogram ----------------
__global__ __launch_bounds__(256) void k_hist(
    const int* __restrict__ cluster, int* __restrict__ counts)
{
    int i = blockIdx.x * 256 + threadIdx.x;
    atomicAdd(counts + cluster[i], 1);
}

// ---------------- parallel exclusive scan: A (block sums) / B (scan sums) / C (offsets) ----
__device__ __forceinline__ int block_excl_scan256(int v, int* lsum, int tid) {
    const int lane = tid & 63, wv = tid >> 6;
    int x = v, u;
    u = __shfl_up(x, 1, 64);  if (lane >= 1)  x += u;
    u = __shfl_up(x, 2, 64);  if (lane >= 2)  x += u;
    u = __shfl_up(x, 4, 64);  if (lane >= 4)  x += u;
    u = __shfl_up(x, 8, 64);  if (lane >= 8)  x += u;
    u = __shfl_up(x, 16, 64); if (lane >= 16) x += u;
    u = __shfl_up(x, 32, 64); if (lane >= 32) x += u;
    if (lane == 63) lsum[wv] = x;
    __syncthreads();
    int woff = 0;
    if (wv > 0) woff += lsum[0];
    if (wv > 1) woff += lsum[1];
    if (wv > 2) woff += lsum[2];
    return woff + x - v;     // exclusive
}

__global__ __launch_bounds__(256) void k_scanA(
    const int* __restrict__ counts, int* __restrict__ partial)
{
    __shared__ int lsum[4];
    int i = blockIdx.x * 256 + threadIdx.x;
    int v = (i < NC) ? counts[i] : 0;
    int e = block_excl_scan256(v, lsum, threadIdx.x);
    if (threadIdx.x == 255) partial[blockIdx.x] = e + v;
}

__global__ __launch_bounds__(256) void k_scanB(int* __restrict__ partial)
{
    __shared__ int lsum[4];
    int tid = threadIdx.x;
    int v = (tid < SCAN_B) ? partial[tid] : 0;
    int e = block_excl_scan256(v, lsum, tid);
    __syncthreads();
    if (tid < SCAN_B) partial[tid] = e;
}

__global__ __launch_bounds__(256) void k_scanC(
    const int* __restrict__ counts, const int* __restrict__ partial,
    int* __restrict__ cursor)
{
    __shared__ int lsum[4];
    int i = blockIdx.x * 256 + threadIdx.x;
    int v = (i < NC) ? counts[i] : 0;
    int e = block_excl_scan256(v, lsum, threadIdx.x);
    if (i < NC) cursor[i] = partial[blockIdx.x] + e;
}

// ---------------- counting sort: scatter ----------------
__global__ __launch_bounds__(256) void k_scatter(
    const int* __restrict__ cluster, int* __restrict__ cursor,
    int* __restrict__ perm, int* __restrict__ pclus)
{
    int i = blockIdx.x * 256 + threadIdx.x;
    int c = cluster[i];
    int pos = atomicAdd(cursor + c, 1);
    perm[pos] = i;
    pclus[pos] = c;
}

// ---------------- point MLP via MFMA, fc1 direct-to-fragment (no LDS) ----------------
// R15: (a) launched as TWO 4096-block dispatches via `bofs` (contiguous tile
// order preserved — NOT a swizzle) so rocprof top-5 reveals the residual
// kernels; (b) fc1 row-sharing: each W1 row + b1 loaded once, used for both
// points A and B (was loaded twice).
// NOTE: blockIdx swizzles on this kernel broke Output 0 in R11-R13 for reasons
// not yet explained — do NOT reorder the grid without an mx-level diff.
__global__ __launch_bounds__(256, 4) void k_points_mfma(
    const float* __restrict__ inv_feats,
    const int* __restrict__ perm, const int* __restrict__ pclus,
    const float* __restrict__ W1, const float* __restrict__ b1,
    const unsigned short* __restrict__ W2bf, const float* __restrict__ b2,
    int bofs, float* __restrict__ mx)
{
    const int tid  = threadIdx.x;
    const int wv   = tid >> 6;
    const int l    = tid & 63;
    const int base = (((bofs + blockIdx.x) * 4 + wv)) * 32;
    const int m16 = l & 15;
    const int g4  = (l >> 4) * 4;
    const int k8  = (l >> 4) * 8;

    const int pA = perm[base + m16];
    const int pB = perm[base + 16 + m16];
    const float4 xA = *(const float4*)(inv_feats + (size_t)pA * 4);
    const float4 xB = *(const float4*)(inv_feats + (size_t)pB * 4);

    // fc1 rows k8..k8+7 and 32+k8..32+k8+7; each row loaded ONCE for both points
#define ROW2(K, QA, QB) float QA, QB; { \
    const float4 w = *(const float4*)(W1 + (size_t)(K) * 4); \
    const float bb = b1[K]; \
    float a = bb; \
    a = fmaf(w.x, xA.x, a); a = fmaf(w.y, xA.y, a); \
    a = fmaf(w.z, xA.z, a); a = fmaf(w.w, xA.w, a); \
    QA = fmaxf(a, 0.f); \
    float b = bb; \
    b = fmaf(w.x, xB.x, b); b = fmaf(w.y, xB.y, b); \
    b = fmaf(w.z, xB.z, b); b = fmaf(w.w, xB.w, b); \
    QB = fmaxf(b, 0.f); }

    i32x4 b00, b01, b10, b11;
    {
        ROW2(k8 + 0, qa0, qb0) ROW2(k8 + 1, qa1, qb1)
        ROW2(k8 + 2, qa2, qb2) ROW2(k8 + 3, qa3, qb3)
        ROW2(k8 + 4, qa4, qb4) ROW2(k8 + 5, qa5, qb5)
        ROW2(k8 + 6, qa6, qb6) ROW2(k8 + 7, qa7, qb7)
        b00[0] = cvtpk(qa0, qa1); b00[1] = cvtpk(qa2, qa3);
        b00[2] = cvtpk(qa4, qa5); b00[3] = cvtpk(qa6, qa7);
        b10[0] = cvtpk(qb0, qb1); b10[1] = cvtpk(qb2, qb3);
        b10[2] = cvtpk(qb4, qb5); b10[3] = cvtpk(qb6, qb7);
    }
    {
        ROW2(32 + k8 + 0, qa0, qb0) ROW2(32 + k8 + 1, qa1, qb1)
        ROW2(32 + k8 + 2, qa2, qb2) ROW2(32 + k8 + 3, qa3, qb3)
        ROW2(32 + k8 + 4, qa4, qb4) ROW2(32 + k8 + 5, qa5, qb5)
        ROW2(32 + k8 + 6, qa6, qb6) ROW2(32 + k8 + 7, qa7, qb7)
        b01[0] = cvtpk(qa0, qa1); b01[1] = cvtpk(qa2, qa3);
        b01[2] = cvtpk(qa4, qa5); b01[3] = cvtpk(qa6, qa7);
        b11[0] = cvtpk(qb0, qb1); b11[1] = cvtpk(qb2, qb3);
        b11[2] = cvtpk(qb4, qb5); b11[3] = cvtpk(qb6, qb7);
    }
#undef ROW2

    // segment masks per 16-pt n-tile (+1 so DPP shifted-in 0 != any key)
    const int cp0 = pclus[base + m16] + 1;
    const int cp1 = pclus[base + 16 + m16] + 1;
    const bool e0a = (DPPSHR(1, cp0) == cp0);
    const bool e0b = (DPPSHR(2, cp0) == cp0);
    const bool e0c = (DPPSHR(4, cp0) == cp0);
    const bool e0d = (DPPSHR(8, cp0) == cp0);
    const bool tl0 = (DPPSHL1(cp0) != cp0);
    const bool e1a = (DPPSHR(1, cp1) == cp1);
    const bool e1b = (DPPSHR(2, cp1) == cp1);
    const bool e1c = (DPPSHR(4, cp1) == cp1);
    const bool e1d = (DPPSHR(8, cp1) == cp1);
    const bool tl1 = (DPPSHL1(cp1) != cp1);
    int* mrow0 = (int*)mx + (size_t)(cp0 - 1) * 128;
    int* mrow1 = (int*)mx + (size_t)(cp1 - 1) * 128;

#define LDA(MB, KK) (*(const i32x4*)(W2bf + (size_t)(kcc + (MB)*16 + m16) * 64 + (KK)*32 + k8))

#define SC4(V, EA, EB, EC, ED) { float _u; \
    _u = __int_as_float(DPPSHR(1, __float_as_int(V))); if (EA) V = fmaxf(V, _u); \
    _u = __int_as_float(DPPSHR(2, __float_as_int(V))); if (EB) V = fmaxf(V, _u); \
    _u = __int_as_float(DPPSHR(4, __float_as_int(V))); if (EC) V = fmaxf(V, _u); \
    _u = __int_as_float(DPPSHR(8, __float_as_int(V))); if (ED) V = fmaxf(V, _u); }

#define EMIT(ACC, MB, EA, EB, EC, ED, TL, MROW) { \
    const float4 bb = *(const float4*)(b2 + kcc + (MB)*16 + g4); \
    float v0 = fmaxf(ACC[0] + bb.x, 0.f); \
    float v1 = fmaxf(ACC[1] + bb.y, 0.f); \
    float v2 = fmaxf(ACC[2] + bb.z, 0.f); \
    float v3 = fmaxf(ACC[3] + bb.w, 0.f); \
    SC4(v0, EA, EB, EC, ED) SC4(v1, EA, EB, EC, ED) \
    SC4(v2, EA, EB, EC, ED) SC4(v3, EA, EB, EC, ED) \
    if (TL) { \
        if (v0 > 0.f) atomicMax(MROW + kcc + (MB)*16 + g4 + 0, __float_as_int(v0)); \
        if (v1 > 0.f) atomicMax(MROW + kcc + (MB)*16 + g4 + 1, __float_as_int(v1)); \
        if (v2 > 0.f) atomicMax(MROW + kcc + (MB)*16 + g4 + 2, __float_as_int(v2)); \
        if (v3 > 0.f) atomicMax(MROW + kcc + (MB)*16 + g4 + 3, __float_as_int(v3)); } }

#define PASS(KC) { \
    const int kcc = (KC) * 64; \
    const i32x4 a00 = LDA(0,0), a01 = LDA(0,1), a10 = LDA(1,0), a11 = LDA(1,1); \
    const i32x4 a20 = LDA(2,0), a21 = LDA(2,1), a30 = LDA(3,0), a31 = LDA(3,1); \
    f32x4v c00 = {0.f,0.f,0.f,0.f}, c01 = {0.f,0.f,0.f,0.f}; \
    f32x4v c10 = {0.f,0.f,0.f,0.f}, c11 = {0.f,0.f,0.f,0.f}; \
    f32x4v c20 = {0.f,0.f,0.f,0.f}, c21 = {0.f,0.f,0.f,0.f}; \
    f32x4v c30 = {0.f,0.f,0.f,0.f}, c31 = {0.f,0.f,0.f,0.f}; \
    c00 = mfma16(a00, b00, c00); c00 = mfma16(a01, b01, c00); \
    c10 = mfma16(a10, b00, c10); c10 = mfma16(a11, b01, c10); \
    c20 = mfma16(a20, b00, c20); c20 = mfma16(a21, b01, c20); \
    c30 = mfma16(a30, b00, c30); c30 = mfma16(a31, b01, c30); \
    c01 = mfma16(a00, b10, c01); c01 = mfma16(a01, b11, c01); \
    c11 = mfma16(a10, b10, c11); c11 = mfma16(a11, b11, c11); \
    c21 = mfma16(a20, b10, c21); c21 = mfma16(a21, b11, c21); \
    c31 = mfma16(a30, b10, c31); c31 = mfma16(a31, b11, c31); \
    EMIT(c00, 0, e0a, e0b, e0c, e0d, tl0, mrow0) \
    EMIT(c10, 1, e0a, e0b, e0c, e0d, tl0, mrow0) \
    EMIT(c20, 2, e0a, e0b, e0c, e0d, tl0, mrow0) \
    EMIT(c30, 3, e0a, e0b, e0c, e0d, tl0, mrow0) \
    EMIT(c01, 0, e1a, e1b, e1c, e1d, tl1, mrow1) \
    EMIT(c11, 1, e1a, e1b, e1c, e1d, tl1, mrow1) \
    EMIT(c21, 2, e1a, e1b, e1c, e1d, tl1, mrow1) \
    EMIT(c31, 3, e1a, e1b, e1c, e1d, tl1, mrow1) }

    PASS(0)
    PASS(1)
#undef PASS
#undef EMIT
#undef SC4
#undef LDA
}

// ---------------- cluster MLP via MFMA: fc3 (128->64), fc4 (64->64) ----------------
__global__ __launch_bounds__(256, 4) void k_cluster_mfma(
    const float* __restrict__ mx,
    const unsigned short* __restrict__ W3bf, const float* __restrict__ b3,
    const unsigned short* __restrict__ W4bf, const float* __restrict__ b4,
    float* __restrict__ fc4out)
{
    __shared__ __align__(16) unsigned short f3[4][32 * 64];
    const int tid = threadIdx.x;
    const int wv  = tid >> 6;
    const int l   = tid & 63;
    const int m16 = l & 15;
    const int g4  = (l >> 4) * 4;
    const int k8  = (l >> 4) * 8;
    const int cbase = (blockIdx.x * 4 + wv) * 32;
    const int cA = cbase + m16;
    const int cB = cbase + 16 + m16;
    const size_t rA = (size_t)min(cA, NC - 1) * 128;
    const size_t rB = (size_t)min(cB, NC - 1) * 128;
    unsigned short* f3w = &f3[wv][0];
    const int swA = (m16 & 7) << 3;
    const int swB = swA;

    f32x4v d00 = {0,0,0,0}, d01 = {0,0,0,0}, d02 = {0,0,0,0}, d03 = {0,0,0,0};
    f32x4v d10 = {0,0,0,0}, d11 = {0,0,0,0}, d12 = {0,0,0,0}, d13 = {0,0,0,0};

#define LD3(MB, KK) (*(const i32x4*)(W3bf + (size_t)((MB)*16 + m16) * 128 + (KK)*32 + k8))
#define FC3STEP(KK) { \
    const float4 vA0 = *(const float4*)(mx + rA + (KK)*32 + k8); \
    const float4 vA1 = *(const float4*)(mx + rA + (KK)*32 + k8 + 4); \
    const float4 vB0 = *(const float4*)(mx + rB + (KK)*32 + k8); \
    const float4 vB1 = *(const float4*)(mx + rB + (KK)*32 + k8 + 4); \
    i32x4 bA = { cvtpk(vA0.x, vA0.y), cvtpk(vA0.z, vA0.w), \
                 cvtpk(vA1.x, vA1.y), cvtpk(vA1.z, vA1.w) }; \
    i32x4 bB = { cvtpk(vB0.x, vB0.y), cvtpk(vB0.z, vB0.w), \
                 cvtpk(vB1.x, vB1.y), cvtpk(vB1.z, vB1.w) }; \
    const i32x4 a0 = LD3(0, KK), a1 = LD3(1, KK), a2 = LD3(2, KK), a3 = LD3(3, KK); \
    d00 = mfma16(a0, bA, d00); d01 = mfma16(a1, bA, d01); \
    d02 = mfma16(a2, bA, d02); d03 = mfma16(a3, bA, d03); \
    d10 = mfma16(a0, bB, d10); d11 = mfma16(a1, bB, d11); \
    d12 = mfma16(a2, bB, d12); d13 = mfma16(a3, bB, d13); }
    FC3STEP(0) FC3STEP(1) FC3STEP(2) FC3STEP(3)
#undef FC3STEP
#undef LD3

#define ST3(DD, MB, CL, SW) { \
    const float4 bb = *(const float4*)(b3 + (MB)*16 + g4); \
    float v0 = fmaxf(DD[0] + bb.x, 0.f); \
    float v1 = fmaxf(DD[1] + bb.y, 0.f); \
    float v2 = fmaxf(DD[2] + bb.z, 0.f); \
    float v3 = fmaxf(DD[3] + bb.w, 0.f); \
    int2 pk = { cvtpk(v0, v1), cvtpk(v2, v3) }; \
    *(int2*)(f3w + (CL)*64 + ((((MB)*16 + g4)) ^ (SW))) = pk; }
    ST3(d00, 0, m16, swA) ST3(d01, 1, m16, swA) ST3(d02, 2, m16, swA) ST3(d03, 3, m16, swA)
    ST3(d10, 0, 16 + m16, swB) ST3(d11, 1, 16 + m16, swB) ST3(d12, 2, 16 + m16, swB) ST3(d13, 3, 16 + m16, swB)
#undef ST3

    f32x4v e00 = {0,0,0,0}, e01 = {0,0,0,0}, e02 = {0,0,0,0}, e03 = {0,0,0,0};
    f32x4v e10 = {0,0,0,0}, e11 = {0,0,0,0}, e12 = {0,0,0,0}, e13 = {0,0,0,0};
#define LD4(MB, KK) (*(const i32x4*)(W4bf + (size_t)((MB)*16 + m16) * 64 + (KK)*32 + k8))
#define FC4STEP(KK) { \
    const i32x4 bA4 = *(const i32x4*)(f3w + m16*64 + (((KK)*32 + k8) ^ swA)); \
    const i32x4 bB4 = *(const i32x4*)(f3w + (16 + m16)*64 + (((KK)*32 + k8) ^ swB)); \
    const i32x4 a0 = LD4(0, KK), a1 = LD4(1, KK), a2 = LD4(2, KK), a3 = LD4(3, KK); \
    e00 = mfma16(a0, bA4, e00); e01 = mfma16(a1, bA4, e01); \
    e02 = mfma16(a2, bA4, e02); e03 = mfma16(a3, bA4, e03); \
    e10 = mfma16(a0, bB4, e10); e11 = mfma16(a1, bB4, e11); \
    e12 = mfma16(a2, bB4, e12); e13 = mfma16(a3, bB4, e13); }
    FC4STEP(0) FC4STEP(1)
#undef FC4STEP
#undef LD4

#define WR(EE, MB, CL) if ((CL) < NC) { \
    const float4 bb = *(const float4*)(b4 + (MB)*16 + g4); \
    float4 o; \
    o.x = fmaxf(EE[0] + bb.x, 0.f); \
    o.y = fmaxf(EE[1] + bb.y, 0.f); \
    o.z = fmaxf(EE[2] + bb.z, 0.f); \
    o.w = fmaxf(EE[3] + bb.w, 0.f); \
    *(float4*)(fc4out + (size_t)(CL)*64 + (MB)*16 + g4) = o; }
    WR(e00, 0, cA) WR(e01, 1, cA) WR(e02, 2, cA) WR(e03, 3, cA)
    WR(e10, 0, cB) WR(e11, 1, cB) WR(e12, 2, cB) WR(e13, 3, cB)
#undef WR
}

// ---------------- fc5 (67->3) + segmented sums ----------------
__global__ __launch_bounds__(256) void k_fc5_sorted(
    const float* __restrict__ points,
    const int* __restrict__ perm, const int* __restrict__ pclus,
    const float* __restrict__ fc4, const float* __restrict__ W5,
    const float* __restrict__ b5, float* __restrict__ sums)
{
    const int t = blockIdx.x * 256 + threadIdx.x;
    const int p = perm[t];
    const int c = pclus[t];
    const float p0 = points[(size_t)p * 3 + 0];
    const float p1 = points[(size_t)p * 3 + 1];
    const float p2 = points[(size_t)p * 3 + 2];
    const float* f4 = fc4 + (size_t)c * 64;

    float a0 = b5[0];
    a0 = fmaf(W5[0], p0, a0); a0 = fmaf(W5[1], p1, a0); a0 = fmaf(W5[2], p2, a0);
    float a1 = b5[1];
    a1 = fmaf(W5[67], p0, a1); a1 = fmaf(W5[68], p1, a1); a1 = fmaf(W5[69], p2, a1);
    float a2 = b5[2];
    a2 = fmaf(W5[134], p0, a2); a2 = fmaf(W5[135], p1, a2); a2 = fmaf(W5[136], p2, a2);

#pragma unroll
    for (int j = 0; j < 64; j += 4) {
        float4 v = *(const float4*)(f4 + j);
        a0 = fmaf(W5[3 + j + 0], v.x, a0);
        a0 = fmaf(W5[3 + j + 1], v.y, a0);
        a0 = fmaf(W5[3 + j + 2], v.z, a0);
        a0 = fmaf(W5[3 + j + 3], v.w, a0);
        a1 = fmaf(W5[70 + j + 0], v.x, a1);
        a1 = fmaf(W5[70 + j + 1], v.y, a1);
        a1 = fmaf(W5[70 + j + 2], v.z, a1);
        a1 = fmaf(W5[70 + j + 3], v.w, a1);
        a2 = fmaf(W5[137 + j + 0], v.x, a2);
        a2 = fmaf(W5[137 + j + 1], v.y, a2);
        a2 = fmaf(W5[137 + j + 2], v.z, a2);
        a2 = fmaf(W5[137 + j + 3], v.w, a2);
    }
    a0 = fmaxf(a0, 0.f);
    a1 = fmaxf(a1, 0.f);
    a2 = fmaxf(a2, 0.f);

    const int lane = threadIdx.x & 63;
    const int cu1  = __shfl_up(c, 1, 64);
    const int cu2  = __shfl_up(c, 2, 64);
    const int cu4  = __shfl_up(c, 4, 64);
    const int cu8  = __shfl_up(c, 8, 64);
    const int cu16 = __shfl_up(c, 16, 64);
    const int cu32 = __shfl_up(c, 32, 64);
    const int cdn  = __shfl_down(c, 1, 64);
    const bool eq0 = (lane >= 1)  && (cu1  == c);
    const bool eq1 = (lane >= 2)  && (cu2  == c);
    const bool eq2 = (lane >= 4)  && (cu4  == c);
    const bool eq3 = (lane >= 8)  && (cu8  == c);
    const bool eq4 = (lane >= 16) && (cu16 == c);
    const bool eq5 = (lane >= 32) && (cu32 == c);
    const bool tail = (lane == 63) || (cdn != c);

    float u0, u1, u2;
    u0 = __shfl_up(a0, 1, 64);  u1 = __shfl_up(a1, 1, 64);  u2 = __shfl_up(a2, 1, 64);
    if (eq0) { a0 += u0; a1 += u1; a2 += u2; }
    u0 = __shfl_up(a0, 2, 64);  u1 = __shfl_up(a1, 2, 64);  u2 = __shfl_up(a2, 2, 64);
    if (eq1) { a0 += u0; a1 += u1; a2 += u2; }
    u0 = __shfl_up(a0, 4, 64);  u1 = __shfl_up(a1, 4, 64);  u2 = __shfl_up(a2, 4, 64);
    if (eq2) { a0 += u0; a1 += u1; a2 += u2; }
    u0 = __shfl_up(a0, 8, 64);  u1 = __shfl_up(a1, 8, 64);  u2 = __shfl_up(a2, 8, 64);
    if (eq3) { a0 += u0; a1 += u1; a2 += u2; }
    u0 = __shfl_up(a0, 16, 64); u1 = __shfl_up(a1, 16, 64); u2 = __shfl_up(a2, 16, 64);
    if (eq4) { a0 += u0; a1 += u1; a2 += u2; }
    u0 = __shfl_up(a0, 32, 64); u1 = __shfl_up(a1, 32, 64); u2 = __shfl_up(a2, 32, 64);
    if (eq5) { a0 += u0; a1 += u1; a2 += u2; }

    if (tail) {
        float* srow = sums + (size_t)c * 3;
        atomicAdd(srow + 0, a0);
        atomicAdd(srow + 1, a1);
        atomicAdd(srow + 2, a2);
    }
}

// ---------------- angles: sigmoid(sums / max(cnt,1)) ----------------
__global__ __launch_bounds__(256) void k_angles(
    const float* __restrict__ sums, const int* __restrict__ counts,
    float* __restrict__ angout)
{
    int c = blockIdx.x * 256 + threadIdx.x;
    if (c >= NC) return;
    const float cnt = fmaxf((float)counts[c], 1.f);
#pragma unroll
    for (int r = 0; r < 3; ++r) {
        float s = sums[(size_t)c * 3 + r] / cnt;
        angout[(size_t)c * 3 + r] = 1.f / (1.f + expf(-s));
    }
}

extern "C" void kernel_launch(void* const* d_in, const int* in_sizes, int n_in,
                              void* d_out, int out_size, void* d_ws, size_t ws_size,
                              hipStream_t stream) {
    const float* points  = (const float*)d_in[0];
    const float* inv     = (const float*)d_in[1];
    const int*   cluster = (const int*)d_in[2];
    const float* W1 = (const float*)d_in[3];
    const float* b1 = (const float*)d_in[4];
    const float* W2 = (const float*)d_in[5];
    const float* b2 = (const float*)d_in[6];
    const float* W3 = (const float*)d_in[7];
    const float* b3 = (const float*)d_in[8];
    const float* W4 = (const float*)d_in[9];
    const float* b4 = (const float*)d_in[10];
    const float* W5 = (const float*)d_in[11];
    const float* b5 = (const float*)d_in[12];

    float* out    = (float*)d_out;
    float* fc4out = out;                       // [C,64]
    float* angout = out + (size_t)NC * 64;     // [C,3]

    // ws layout (zeroed region first):
    //   counts[NC] | sums[NC*3] | mx[NC*128] || cursor[NC] | perm[N] | pclus[N]
    //   | W2bf[8192] | W3bf[8192] | W4bf[4096] (u16) | partial[256]
    int*   counts = (int*)d_ws;
    float* sums   = (float*)(counts + NC);
    float* mx     = sums + (size_t)NC * 3;
    int*   cursor = (int*)(mx + (size_t)NC * 128);
    int*   perm   = cursor + NC;
    int*   pclus  = perm + N_PTS;
    unsigned short* W2bf = (unsigned short*)(pclus + N_PTS);
    unsigned short* W3bf = W2bf + 8192;
    unsigned short* W4bf = W3bf + 8192;
    int*   partial = (int*)(W4bf + 4096);

    hipMemsetAsync(d_ws, 0, (size_t)(NC + NC * 3 + NC * 128) * sizeof(float), stream);

    k_prep         <<<80, 256, 0, stream>>>(W2, W3, W4, W2bf, W3bf, W4bf);
    k_hist         <<<N_PTS / 256, 256, 0, stream>>>(cluster, counts);
    k_scanA        <<<SCAN_B, 256, 0, stream>>>(counts, partial);
    k_scanB        <<<1, 256, 0, stream>>>(partial);
    k_scanC        <<<SCAN_B, 256, 0, stream>>>(counts, partial, cursor);
    k_scatter      <<<N_PTS / 256, 256, 0, stream>>>(cluster, cursor, perm, pclus);
    k_points_mfma  <<<4096, 256, 0, stream>>>(inv, perm, pclus, W1, b1, W2bf, b2, 0, mx);
    k_points_mfma  <<<4096, 256, 0, stream>>>(inv, perm, pclus, W1, b1, W2bf, b2, 4096, mx);
    k_cluster_mfma <<<(NC + 127) / 128, 256, 0, stream>>>(mx, W3bf, b3, W4bf, b4, fc4out);
    k_fc5_sorted   <<<N_PTS / 256, 256, 0, stream>>>(points, perm, pclus, fc4out, W5, b5, sums);
    k_angles       <<<(NC + 255) / 256, 256, 0, stream>>>(sums, counts, angout);
}

// Round 16
// 295.676 us; speedup vs baseline: 1.1434x; 1.1434x over previous
//
#include <hip/hip_runtime.h>

#define N_PTS 1048576
#define NC 50000
#define SCAN_B 196   // scan blocks: 196*256 = 50176 >= NC

typedef int   i32x4  __attribute__((ext_vector_type(4)));
typedef float f32x4v __attribute__((ext_vector_type(4)));

__device__ __forceinline__ unsigned short bf16rne(float f) {
    unsigned u = __float_as_uint(f);
    u = (u + 0x7fffu + ((u >> 16) & 1u)) >> 16;
    return (unsigned short)u;
}
__device__ __forceinline__ f32x4v mfma16(i32x4 a, i32x4 b, f32x4v c) {
    asm("v_mfma_f32_16x16x32_bf16 %0, %1, %2, %0" : "+v"(c) : "v"(a), "v"(b));
    return c;
}
__device__ __forceinline__ int cvtpk(float lo, float hi) {
    int r;
    asm("v_cvt_pk_bf16_f32 %0, %1, %2" : "=v"(r) : "v"(lo), "v"(hi));
    return r;
}

// DPP within 16-lane rows; bound_ctrl=1 -> shifted-in 0.
#define DPPSHR(D, X) __builtin_amdgcn_update_dpp(0, (X), 0x110 | (D), 0xf, 0xf, true)
#define DPPSHL1(X)   __builtin_amdgcn_update_dpp(0, (X), 0x101, 0xf, 0xf, true)

// ---------------- histogram + fused weight prep (W2/W3/W4 fp32 -> bf16) ----------------
__global__ __launch_bounds__(256) void k_histprep(
    const int* __restrict__ cluster, int* __restrict__ counts,
    const float* __restrict__ W2, const float* __restrict__ W3,
    const float* __restrict__ W4,
    unsigned short* __restrict__ W2bf, unsigned short* __restrict__ W3bf,
    unsigned short* __restrict__ W4bf)
{
    int i = blockIdx.x * 256 + threadIdx.x;
    if (i < 8192)       W2bf[i]         = bf16rne(W2[i]);
    else if (i < 16384) W3bf[i - 8192]  = bf16rne(W3[i - 8192]);
    else if (i < 20480) W4bf[i - 16384] = bf16rne(W4[i - 16384]);
    atomicAdd(counts + cluster[i], 1);
}

// ---------------- parallel exclusive scan (2 kernels; scanC self-computes prefix) ----
__device__ __forceinline__ int block_excl_scan256(int v, int* lsum, int tid) {
    const int lane = tid & 63, wv = tid >> 6;
    int x = v, u;
    u = __shfl_up(x, 1, 64);  if (lane >= 1)  x += u;
    u = __shfl_up(x, 2, 64);  if (lane >= 2)  x += u;
    u = __shfl_up(x, 4, 64);  if (lane >= 4)  x += u;
    u = __shfl_up(x, 8, 64);  if (lane >= 8)  x += u;
    u = __shfl_up(x, 16, 64); if (lane >= 16) x += u;
    u = __shfl_up(x, 32, 64); if (lane >= 32) x += u;
    if (lane == 63) lsum[wv] = x;
    __syncthreads();
    int woff = 0;
    if (wv > 0) woff += lsum[0];
    if (wv > 1) woff += lsum[1];
    if (wv > 2) woff += lsum[2];
    return woff + x - v;     // exclusive
}

__global__ __launch_bounds__(256) void k_scanA(
    const int* __restrict__ counts, int* __restrict__ partial)
{
    __shared__ int lsum[4];
    int i = blockIdx.x * 256 + threadIdx.x;
    int v = (i < NC) ? counts[i] : 0;
    int e = block_excl_scan256(v, lsum, threadIdx.x);
    if (threadIdx.x == 255) partial[blockIdx.x] = e + v;
}

__global__ __launch_bounds__(256) void k_scanC(
    const int* __restrict__ counts, const int* __restrict__ partial,
    int* __restrict__ cursor)
{
    __shared__ int lsum[4];
    __shared__ int tot;
    const int tid = threadIdx.x;
    // prefix over partial[0..blockIdx.x): in-block parallel reduction
    int pv = (tid < SCAN_B && tid < blockIdx.x) ? partial[tid] : 0;
    int pe = block_excl_scan256(pv, lsum, tid);
    if (tid == 255) tot = pe + pv;
    __syncthreads();
    const int pref = tot;
    __syncthreads();
    int i = blockIdx.x * 256 + tid;
    int v = (i < NC) ? counts[i] : 0;
    int e = block_excl_scan256(v, lsum, tid);
    if (i < NC) cursor[i] = pref + e;
}

// ---------------- counting sort: scatter (+ optional payload sort) ----------------
// SORTED mode: scatter the 16B inv_feats row and padded points row alongside the
// key, so downstream kernels read coalesced (kills the 4-5x gather line
// overfetch seen in k_points FETCH_SIZE). Gather mode = R14 behavior.
template<bool SORTED>
__global__ __launch_bounds__(256) void k_scatter(
    const int* __restrict__ cluster, const float* __restrict__ inv,
    const float* __restrict__ points, int* __restrict__ cursor,
    int* __restrict__ perm, int* __restrict__ pclus,
    float4* __restrict__ invs, float4* __restrict__ ptsc)
{
    int i = blockIdx.x * 256 + threadIdx.x;
    int c = cluster[i];
    int pos = atomicAdd(cursor + c, 1);
    pclus[pos] = c;
    if (SORTED) {
        invs[pos] = *(const float4*)(inv + (size_t)i * 4);
        float4 pt = { points[(size_t)i * 3 + 0], points[(size_t)i * 3 + 1],
                      points[(size_t)i * 3 + 2], 0.f };
        ptsc[pos] = pt;
    } else {
        perm[pos] = i;
    }
}

// ---------------- point MLP via MFMA, fc1 direct-to-fragment (no LDS) ----------------
// NOTE: blockIdx swizzles on this kernel broke Output 0 in R11-R13 for reasons
// not yet explained — do NOT reorder the grid without an mx-level diff.
template<bool SORTED>
__global__ __launch_bounds__(256, 4) void k_points_mfma(
    const float* __restrict__ inv_feats,
    const int* __restrict__ perm, const int* __restrict__ pclus,
    const float4* __restrict__ invs,
    const float* __restrict__ W1, const float* __restrict__ b1,
    const unsigned short* __restrict__ W2bf, const float* __restrict__ b2,
    float* __restrict__ mx)
{
    const int tid  = threadIdx.x;
    const int wv   = tid >> 6;
    const int l    = tid & 63;
    const int base = (blockIdx.x * 4 + wv) * 32;
    const int m16 = l & 15;
    const int g4  = (l >> 4) * 4;
    const int k8  = (l >> 4) * 8;

    float4 xA, xB;
    if (SORTED) {
        xA = invs[base + m16];
        xB = invs[base + 16 + m16];
    } else {
        const int pA = perm[base + m16];
        const int pB = perm[base + 16 + m16];
        xA = *(const float4*)(inv_feats + (size_t)pA * 4);
        xB = *(const float4*)(inv_feats + (size_t)pB * 4);
    }

    // fc1 rows k8..k8+7 and 32+k8..+7; each W1 row loaded once for both points
#define ROW2(K, QA, QB) float QA, QB; { \
    const float4 w = *(const float4*)(W1 + (size_t)(K) * 4); \
    const float bb = b1[K]; \
    float a = bb; \
    a = fmaf(w.x, xA.x, a); a = fmaf(w.y, xA.y, a); \
    a = fmaf(w.z, xA.z, a); a = fmaf(w.w, xA.w, a); \
    QA = fmaxf(a, 0.f); \
    float b = bb; \
    b = fmaf(w.x, xB.x, b); b = fmaf(w.y, xB.y, b); \
    b = fmaf(w.z, xB.z, b); b = fmaf(w.w, xB.w, b); \
    QB = fmaxf(b, 0.f); }

    i32x4 b00, b01, b10, b11;
    {
        ROW2(k8 + 0, qa0, qb0) ROW2(k8 + 1, qa1, qb1)
        ROW2(k8 + 2, qa2, qb2) ROW2(k8 + 3, qa3, qb3)
        ROW2(k8 + 4, qa4, qb4) ROW2(k8 + 5, qa5, qb5)
        ROW2(k8 + 6, qa6, qb6) ROW2(k8 + 7, qa7, qb7)
        b00[0] = cvtpk(qa0, qa1); b00[1] = cvtpk(qa2, qa3);
        b00[2] = cvtpk(qa4, qa5); b00[3] = cvtpk(qa6, qa7);
        b10[0] = cvtpk(qb0, qb1); b10[1] = cvtpk(qb2, qb3);
        b10[2] = cvtpk(qb4, qb5); b10[3] = cvtpk(qb6, qb7);
    }
    {
        ROW2(32 + k8 + 0, qa0, qb0) ROW2(32 + k8 + 1, qa1, qb1)
        ROW2(32 + k8 + 2, qa2, qb2) ROW2(32 + k8 + 3, qa3, qb3)
        ROW2(32 + k8 + 4, qa4, qb4) ROW2(32 + k8 + 5, qa5, qb5)
        ROW2(32 + k8 + 6, qa6, qb6) ROW2(32 + k8 + 7, qa7, qb7)
        b01[0] = cvtpk(qa0, qa1); b01[1] = cvtpk(qa2, qa3);
        b01[2] = cvtpk(qa4, qa5); b01[3] = cvtpk(qa6, qa7);
        b11[0] = cvtpk(qb0, qb1); b11[1] = cvtpk(qb2, qb3);
        b11[2] = cvtpk(qb4, qb5); b11[3] = cvtpk(qb6, qb7);
    }
#undef ROW2

    // segment masks per 16-pt n-tile (+1 so DPP shifted-in 0 != any key)
    const int cp0 = pclus[base + m16] + 1;
    const int cp1 = pclus[base + 16 + m16] + 1;
    const bool e0a = (DPPSHR(1, cp0) == cp0);
    const bool e0b = (DPPSHR(2, cp0) == cp0);
    const bool e0c = (DPPSHR(4, cp0) == cp0);
    const bool e0d = (DPPSHR(8, cp0) == cp0);
    const bool tl0 = (DPPSHL1(cp0) != cp0);
    const bool e1a = (DPPSHR(1, cp1) == cp1);
    const bool e1b = (DPPSHR(2, cp1) == cp1);
    const bool e1c = (DPPSHR(4, cp1) == cp1);
    const bool e1d = (DPPSHR(8, cp1) == cp1);
    const bool tl1 = (DPPSHL1(cp1) != cp1);
    int* mrow0 = (int*)mx + (size_t)(cp0 - 1) * 128;
    int* mrow1 = (int*)mx + (size_t)(cp1 - 1) * 128;

#define LDA(MB, KK) (*(const i32x4*)(W2bf + (size_t)(kcc + (MB)*16 + m16) * 64 + (KK)*32 + k8))

#define SC4(V, EA, EB, EC, ED) { float _u; \
    _u = __int_as_float(DPPSHR(1, __float_as_int(V))); if (EA) V = fmaxf(V, _u); \
    _u = __int_as_float(DPPSHR(2, __float_as_int(V))); if (EB) V = fmaxf(V, _u); \
    _u = __int_as_float(DPPSHR(4, __float_as_int(V))); if (EC) V = fmaxf(V, _u); \
    _u = __int_as_float(DPPSHR(8, __float_as_int(V))); if (ED) V = fmaxf(V, _u); }

#define EMIT(ACC, MB, EA, EB, EC, ED, TL, MROW) { \
    const float4 bb = *(const float4*)(b2 + kcc + (MB)*16 + g4); \
    float v0 = fmaxf(ACC[0] + bb.x, 0.f); \
    float v1 = fmaxf(ACC[1] + bb.y, 0.f); \
    float v2 = fmaxf(ACC[2] + bb.z, 0.f); \
    float v3 = fmaxf(ACC[3] + bb.w, 0.f); \
    SC4(v0, EA, EB, EC, ED) SC4(v1, EA, EB, EC, ED) \
    SC4(v2, EA, EB, EC, ED) SC4(v3, EA, EB, EC, ED) \
    if (TL) { \
        if (v0 > 0.f) atomicMax(MROW + kcc + (MB)*16 + g4 + 0, __float_as_int(v0)); \
        if (v1 > 0.f) atomicMax(MROW + kcc + (MB)*16 + g4 + 1, __float_as_int(v1)); \
        if (v2 > 0.f) atomicMax(MROW + kcc + (MB)*16 + g4 + 2, __float_as_int(v2)); \
        if (v3 > 0.f) atomicMax(MROW + kcc + (MB)*16 + g4 + 3, __float_as_int(v3)); } }

#define PASS(KC) { \
    const int kcc = (KC) * 64; \
    const i32x4 a00 = LDA(0,0), a01 = LDA(0,1), a10 = LDA(1,0), a11 = LDA(1,1); \
    const i32x4 a20 = LDA(2,0), a21 = LDA(2,1), a30 = LDA(3,0), a31 = LDA(3,1); \
    f32x4v c00 = {0.f,0.f,0.f,0.f}, c01 = {0.f,0.f,0.f,0.f}; \
    f32x4v c10 = {0.f,0.f,0.f,0.f}, c11 = {0.f,0.f,0.f,0.f}; \
    f32x4v c20 = {0.f,0.f,0.f,0.f}, c21 = {0.f,0.f,0.f,0.f}; \
    f32x4v c30 = {0.f,0.f,0.f,0.f}, c31 = {0.f,0.f,0.f,0.f}; \
    c00 = mfma16(a00, b00, c00); c00 = mfma16(a01, b01, c00); \
    c10 = mfma16(a10, b00, c10); c10 = mfma16(a11, b01, c10); \
    c20 = mfma16(a20, b00, c20); c20 = mfma16(a21, b01, c20); \
    c30 = mfma16(a30, b00, c30); c30 = mfma16(a31, b01, c30); \
    c01 = mfma16(a00, b10, c01); c01 = mfma16(a01, b11, c01); \
    c11 = mfma16(a10, b10, c11); c11 = mfma16(a11, b11, c11); \
    c21 = mfma16(a20, b10, c21); c21 = mfma16(a21, b11, c21); \
    c31 = mfma16(a30, b10, c31); c31 = mfma16(a31, b11, c31); \
    EMIT(c00, 0, e0a, e0b, e0c, e0d, tl0, mrow0) \
    EMIT(c10, 1, e0a, e0b, e0c, e0d, tl0, mrow0) \
    EMIT(c20, 2, e0a, e0b, e0c, e0d, tl0, mrow0) \
    EMIT(c30, 3, e0a, e0b, e0c, e0d, tl0, mrow0) \
    EMIT(c01, 0, e1a, e1b, e1c, e1d, tl1, mrow1) \
    EMIT(c11, 1, e1a, e1b, e1c, e1d, tl1, mrow1) \
    EMIT(c21, 2, e1a, e1b, e1c, e1d, tl1, mrow1) \
    EMIT(c31, 3, e1a, e1b, e1c, e1d, tl1, mrow1) }

    PASS(0)
    PASS(1)
#undef PASS
#undef EMIT
#undef SC4
#undef LDA
}

// ---------------- cluster MLP via MFMA: fc3 (128->64), fc4 (64->64) ----------------
__global__ __launch_bounds__(256, 4) void k_cluster_mfma(
    const float* __restrict__ mx,
    const unsigned short* __restrict__ W3bf, const float* __restrict__ b3,
    const unsigned short* __restrict__ W4bf, const float* __restrict__ b4,
    float* __restrict__ fc4out)
{
    __shared__ __align__(16) unsigned short f3[4][32 * 64];
    const int tid = threadIdx.x;
    const int wv  = tid >> 6;
    const int l   = tid & 63;
    const int m16 = l & 15;
    const int g4  = (l >> 4) * 4;
    const int k8  = (l >> 4) * 8;
    const int cbase = (blockIdx.x * 4 + wv) * 32;
    const int cA = cbase + m16;
    const int cB = cbase + 16 + m16;
    const size_t rA = (size_t)min(cA, NC - 1) * 128;
    const size_t rB = (size_t)min(cB, NC - 1) * 128;
    unsigned short* f3w = &f3[wv][0];
    const int swA = (m16 & 7) << 3;
    const int swB = swA;

    f32x4v d00 = {0,0,0,0}, d01 = {0,0,0,0}, d02 = {0,0,0,0}, d03 = {0,0,0,0};
    f32x4v d10 = {0,0,0,0}, d11 = {0,0,0,0}, d12 = {0,0,0,0}, d13 = {0,0,0,0};

#define LD3(MB, KK) (*(const i32x4*)(W3bf + (size_t)((MB)*16 + m16) * 128 + (KK)*32 + k8))
#define FC3STEP(KK) { \
    const float4 vA0 = *(const float4*)(mx + rA + (KK)*32 + k8); \
    const float4 vA1 = *(const float4*)(mx + rA + (KK)*32 + k8 + 4); \
    const float4 vB0 = *(const float4*)(mx + rB + (KK)*32 + k8); \
    const float4 vB1 = *(const float4*)(mx + rB + (KK)*32 + k8 + 4); \
    i32x4 bA = { cvtpk(vA0.x, vA0.y), cvtpk(vA0.z, vA0.w), \
                 cvtpk(vA1.x, vA1.y), cvtpk(vA1.z, vA1.w) }; \
    i32x4 bB = { cvtpk(vB0.x, vB0.y), cvtpk(vB0.z, vB0.w), \
                 cvtpk(vB1.x, vB1.y), cvtpk(vB1.z, vB1.w) }; \
    const i32x4 a0 = LD3(0, KK), a1 = LD3(1, KK), a2 = LD3(2, KK), a3 = LD3(3, KK); \
    d00 = mfma16(a0, bA, d00); d01 = mfma16(a1, bA, d01); \
    d02 = mfma16(a2, bA, d02); d03 = mfma16(a3, bA, d03); \
    d10 = mfma16(a0, bB, d10); d11 = mfma16(a1, bB, d11); \
    d12 = mfma16(a2, bB, d12); d13 = mfma16(a3, bB, d13); }
    FC3STEP(0) FC3STEP(1) FC3STEP(2) FC3STEP(3)
#undef FC3STEP
#undef LD3

#define ST3(DD, MB, CL, SW) { \
    const float4 bb = *(const float4*)(b3 + (MB)*16 + g4); \
    float v0 = fmaxf(DD[0] + bb.x, 0.f); \
    float v1 = fmaxf(DD[1] + bb.y, 0.f); \
    float v2 = fmaxf(DD[2] + bb.z, 0.f); \
    float v3 = fmaxf(DD[3] + bb.w, 0.f); \
    int2 pk = { cvtpk(v0, v1), cvtpk(v2, v3) }; \
    *(int2*)(f3w + (CL)*64 + ((((MB)*16 + g4)) ^ (SW))) = pk; }
    ST3(d00, 0, m16, swA) ST3(d01, 1, m16, swA) ST3(d02, 2, m16, swA) ST3(d03, 3, m16, swA)
    ST3(d10, 0, 16 + m16, swB) ST3(d11, 1, 16 + m16, swB) ST3(d12, 2, 16 + m16, swB) ST3(d13, 3, 16 + m16, swB)
#undef ST3

    f32x4v e00 = {0,0,0,0}, e01 = {0,0,0,0}, e02 = {0,0,0,0}, e03 = {0,0,0,0};
    f32x4v e10 = {0,0,0,0}, e11 = {0,0,0,0}, e12 = {0,0,0,0}, e13 = {0,0,0,0};
#define LD4(MB, KK) (*(const i32x4*)(W4bf + (size_t)((MB)*16 + m16) * 64 + (KK)*32 + k8))
#define FC4STEP(KK) { \
    const i32x4 bA4 = *(const i32x4*)(f3w + m16*64 + (((KK)*32 + k8) ^ swA)); \
    const i32x4 bB4 = *(const i32x4*)(f3w + (16 + m16)*64 + (((KK)*32 + k8) ^ swB)); \
    const i32x4 a0 = LD4(0, KK), a1 = LD4(1, KK), a2 = LD4(2, KK), a3 = LD4(3, KK); \
    e00 = mfma16(a0, bA4, e00); e01 = mfma16(a1, bA4, e01); \
    e02 = mfma16(a2, bA4, e02); e03 = mfma16(a3, bA4, e03); \
    e10 = mfma16(a0, bB4, e10); e11 = mfma16(a1, bB4, e11); \
    e12 = mfma16(a2, bB4, e12); e13 = mfma16(a3, bB4, e13); }
    FC4STEP(0) FC4STEP(1)
#undef FC4STEP
#undef LD4

#define WR(EE, MB, CL) if ((CL) < NC) { \
    const float4 bb = *(const float4*)(b4 + (MB)*16 + g4); \
    float4 o; \
    o.x = fmaxf(EE[0] + bb.x, 0.f); \
    o.y = fmaxf(EE[1] + bb.y, 0.f); \
    o.z = fmaxf(EE[2] + bb.z, 0.f); \
    o.w = fmaxf(EE[3] + bb.w, 0.f); \
    *(float4*)(fc4out + (size_t)(CL)*64 + (MB)*16 + g4) = o; }
    WR(e00, 0, cA) WR(e01, 1, cA) WR(e02, 2, cA) WR(e03, 3, cA)
    WR(e10, 0, cB) WR(e11, 1, cB) WR(e12, 2, cB) WR(e13, 3, cB)
#undef WR
}

// ---------------- fc5 (67->3) + segmented sums ----------------
template<bool SORTED>
__global__ __launch_bounds__(256) void k_fc5_sorted(
    const float* __restrict__ points,
    const int* __restrict__ perm, const int* __restrict__ pclus,
    const float4* __restrict__ ptsc,
    const float* __restrict__ fc4, const float* __restrict__ W5,
    const float* __restrict__ b5, float* __restrict__ sums)
{
    const int t = blockIdx.x * 256 + threadIdx.x;
    const int c = pclus[t];
    float p0, p1, p2;
    if (SORTED) {
        const float4 pt = ptsc[t];
        p0 = pt.x; p1 = pt.y; p2 = pt.z;
    } else {
        const int p = perm[t];
        p0 = points[(size_t)p * 3 + 0];
        p1 = points[(size_t)p * 3 + 1];
        p2 = points[(size_t)p * 3 + 2];
    }
    const float* f4 = fc4 + (size_t)c * 64;

    float a0 = b5[0];
    a0 = fmaf(W5[0], p0, a0); a0 = fmaf(W5[1], p1, a0); a0 = fmaf(W5[2], p2, a0);
    float a1 = b5[1];
    a1 = fmaf(W5[67], p0, a1); a1 = fmaf(W5[68], p1, a1); a1 = fmaf(W5[69], p2, a1);
    float a2 = b5[2];
    a2 = fmaf(W5[134], p0, a2); a2 = fmaf(W5[135], p1, a2); a2 = fmaf(W5[136], p2, a2);

#pragma unroll
    for (int j = 0; j < 64; j += 4) {
        float4 v = *(const float4*)(f4 + j);
        a0 = fmaf(W5[3 + j + 0], v.x, a0);
        a0 = fmaf(W5[3 + j + 1], v.y, a0);
        a0 = fmaf(W5[3 + j + 2], v.z, a0);
        a0 = fmaf(W5[3 + j + 3], v.w, a0);
        a1 = fmaf(W5[70 + j + 0], v.x, a1);
        a1 = fmaf(W5[70 + j + 1], v.y, a1);
        a1 = fmaf(W5[70 + j + 2], v.z, a1);
        a1 = fmaf(W5[70 + j + 3], v.w, a1);
        a2 = fmaf(W5[137 + j + 0], v.x, a2);
        a2 = fmaf(W5[137 + j + 1], v.y, a2);
        a2 = fmaf(W5[137 + j + 2], v.z, a2);
        a2 = fmaf(W5[137 + j + 3], v.w, a2);
    }
    a0 = fmaxf(a0, 0.f);
    a1 = fmaxf(a1, 0.f);
    a2 = fmaxf(a2, 0.f);

    const int lane = threadIdx.x & 63;
    const int cu1  = __shfl_up(c, 1, 64);
    const int cu2  = __shfl_up(c, 2, 64);
    const int cu4  = __shfl_up(c, 4, 64);
    const int cu8  = __shfl_up(c, 8, 64);
    const int cu16 = __shfl_up(c, 16, 64);
    const int cu32 = __shfl_up(c, 32, 64);
    const int cdn  = __shfl_down(c, 1, 64);
    const bool eq0 = (lane >= 1)  && (cu1  == c);
    const bool eq1 = (lane >= 2)  && (cu2  == c);
    const bool eq2 = (lane >= 4)  && (cu4  == c);
    const bool eq3 = (lane >= 8)  && (cu8  == c);
    const bool eq4 = (lane >= 16) && (cu16 == c);
    const bool eq5 = (lane >= 32) && (cu32 == c);
    const bool tail = (lane == 63) || (cdn != c);

    float u0, u1, u2;
    u0 = __shfl_up(a0, 1, 64);  u1 = __shfl_up(a1, 1, 64);  u2 = __shfl_up(a2, 1, 64);
    if (eq0) { a0 += u0; a1 += u1; a2 += u2; }
    u0 = __shfl_up(a0, 2, 64);  u1 = __shfl_up(a1, 2, 64);  u2 = __shfl_up(a2, 2, 64);
    if (eq1) { a0 += u0; a1 += u1; a2 += u2; }
    u0 = __shfl_up(a0, 4, 64);  u1 = __shfl_up(a1, 4, 64);  u2 = __shfl_up(a2, 4, 64);
    if (eq2) { a0 += u0; a1 += u1; a2 += u2; }
    u0 = __shfl_up(a0, 8, 64);  u1 = __shfl_up(a1, 8, 64);  u2 = __shfl_up(a2, 8, 64);
    if (eq3) { a0 += u0; a1 += u1; a2 += u2; }
    u0 = __shfl_up(a0, 16, 64); u1 = __shfl_up(a1, 16, 64); u2 = __shfl_up(a2, 16, 64);
    if (eq4) { a0 += u0; a1 += u1; a2 += u2; }
    u0 = __shfl_up(a0, 32, 64); u1 = __shfl_up(a1, 32, 64); u2 = __shfl_up(a2, 32, 64);
    if (eq5) { a0 += u0; a1 += u1; a2 += u2; }

    if (tail) {
        float* srow = sums + (size_t)c * 3;
        atomicAdd(srow + 0, a0);
        atomicAdd(srow + 1, a1);
        atomicAdd(srow + 2, a2);
    }
}

// ---------------- angles: sigmoid(sums / max(cnt,1)) ----------------
__global__ __launch_bounds__(256) void k_angles(
    const float* __restrict__ sums, const int* __restrict__ counts,
    float* __restrict__ angout)
{
    int c = blockIdx.x * 256 + threadIdx.x;
    if (c >= NC) return;
    const float cnt = fmaxf((float)counts[c], 1.f);
#pragma unroll
    for (int r = 0; r < 3; ++r) {
        float s = sums[(size_t)c * 3 + r] / cnt;
        angout[(size_t)c * 3 + r] = 1.f / (1.f + expf(-s));
    }
}

extern "C" void kernel_launch(void* const* d_in, const int* in_sizes, int n_in,
                              void* d_out, int out_size, void* d_ws, size_t ws_size,
                              hipStream_t stream) {
    const float* points  = (const float*)d_in[0];
    const float* inv     = (const float*)d_in[1];
    const int*   cluster = (const int*)d_in[2];
    const float* W1 = (const float*)d_in[3];
    const float* b1 = (const float*)d_in[4];
    const float* W2 = (const float*)d_in[5];
    const float* b2 = (const float*)d_in[6];
    const float* W3 = (const float*)d_in[7];
    const float* b3 = (const float*)d_in[8];
    const float* W4 = (const float*)d_in[9];
    const float* b4 = (const float*)d_in[10];
    const float* W5 = (const float*)d_in[11];
    const float* b5 = (const float*)d_in[12];

    float* out    = (float*)d_out;
    float* fc4out = out;                       // [C,64]
    float* angout = out + (size_t)NC * 64;     // [C,3]

    // ws layout (zeroed region first):
    //   counts[NC] | sums[NC*3] | mx[NC*128] || cursor[NC] | pclus[N]
    //   | W2bf[8192] | W3bf[8192] | W4bf[4096] (u16) | partial[256] | perm[N]
    //   | invs[N float4] | ptsc[N float4]   (payload-sort region, optional)
    int*   counts = (int*)d_ws;
    float* sums   = (float*)(counts + NC);
    float* mx     = sums + (size_t)NC * 3;
    int*   cursor = (int*)(mx + (size_t)NC * 128);
    int*   pclus  = cursor + NC;
    unsigned short* W2bf = (unsigned short*)(pclus + N_PTS);
    unsigned short* W3bf = W2bf + 8192;
    unsigned short* W4bf = W3bf + 8192;
    int*   partial = (int*)(W4bf + 4096);
    int*   perm    = partial + 256;
    float4* invs   = (float4*)(perm + N_PTS);
    float4* ptsc   = invs + N_PTS;
    const size_t needed_sorted = (size_t)((char*)(ptsc + N_PTS) - (char*)d_ws);
    const bool sorted_mode = ws_size >= needed_sorted;

    hipMemsetAsync(d_ws, 0, (size_t)(NC + NC * 3 + NC * 128) * sizeof(float), stream);

    k_histprep <<<N_PTS / 256, 256, 0, stream>>>(cluster, counts, W2, W3, W4, W2bf, W3bf, W4bf);
    k_scanA    <<<SCAN_B, 256, 0, stream>>>(counts, partial);
    k_scanC    <<<SCAN_B, 256, 0, stream>>>(counts, partial, cursor);
    if (sorted_mode) {
        k_scatter<true>     <<<N_PTS / 256, 256, 0, stream>>>(cluster, inv, points, cursor, perm, pclus, invs, ptsc);
        k_points_mfma<true> <<<N_PTS / 128, 256, 0, stream>>>(inv, perm, pclus, invs, W1, b1, W2bf, b2, mx);
    } else {
        k_scatter<false>    <<<N_PTS / 256, 256, 0, stream>>>(cluster, inv, points, cursor, perm, pclus, invs, ptsc);
        k_points_mfma<false><<<N_PTS / 128, 256, 0, stream>>>(inv, perm, pclus, invs, W1, b1, W2bf, b2, mx);
    }
    k_cluster_mfma <<<(NC + 127) / 128, 256, 0, stream>>>(mx, W3bf, b3, W4bf, b4, fc4out);
    if (sorted_mode) {
        k_fc5_sorted<true>  <<<N_PTS / 256, 256, 0, stream>>>(points, perm, pclus, ptsc, fc4out, W5, b5, sums);
    } else {
        k_fc5_sorted<false> <<<N_PTS / 256, 256, 0, stream>>>(points, perm, pclus, ptsc, fc4out, W5, b5, sums);
    }
    k_angles <<<(NC + 255) / 256, 256, 0, stream>>>(sums, counts, angout);
}